// Round 3
// baseline (671.299 us; speedup 1.0000x reference)
//
#include <hip/hip_runtime.h>
#include <hip/hip_bf16.h>

#define DIN 128
#define HC  128
#define NH  4

// ---------------------------------------------------------------------------
// h = x @ W + b_lin  (h stored as bf16), fused per-node attention scalars:
//   ali[n,h] = sum_c h[n,h,c] * att[0,h,c]        (fp32, from fp32 acc)
//   alj[n,h] = sum_c h[n,h,c] * att[0,h,32+c]
// W (64 KB fp32) staged in LDS once per block; grid-stride, 2 rows/block-iter.
// ---------------------------------------------------------------------------
__global__ __launch_bounds__(256) void linear_fused(
    const float* __restrict__ x, const float* __restrict__ W,
    const float* __restrict__ b, const float* __restrict__ att,
    __hip_bfloat16* __restrict__ h, float* __restrict__ ali,
    float* __restrict__ alj, int n)
{
    __shared__ float Ws[DIN * HC];    // 64 KB
    __shared__ float xs[2][DIN];
    for (int idx = threadIdx.x; idx < DIN * HC; idx += 256)
        Ws[idx] = W[idx];

    const int col  = threadIdx.x & 127;   // output column 0..127
    const int rsub = threadIdx.x >> 7;    // 0 or 1 (row within pair)
    const int hh   = col >> 5;            // head 0..3
    const int cc   = col & 31;            // channel 0..31
    const float ai   = att[hh * 64 + cc];
    const float aj   = att[hh * 64 + 32 + cc];
    const float bcol = b[col];
    __syncthreads();

    for (int row0 = blockIdx.x * 2; row0 < n; row0 += gridDim.x * 2) {
        const int row = row0 + rsub;
        if (row < n) xs[rsub][col] = x[(size_t)row * DIN + col];
        __syncthreads();
        if (row < n) {
            float acc = bcol;
            #pragma unroll
            for (int k = 0; k < DIN; ++k)
                acc = fmaf(xs[rsub][k], Ws[k * HC + col], acc);
            h[(size_t)row * HC + col] = __float2bfloat16(acc);

            float vi = acc * ai;
            float vj = acc * aj;
            #pragma unroll
            for (int m = 16; m; m >>= 1) {
                vi += __shfl_xor(vi, m, 32);
                vj += __shfl_xor(vj, m, 32);
            }
            if (cc == 0) {
                ali[row * NH + hh] = vi;
                alj[row * NH + hh] = vj;
            }
        }
        __syncthreads();
    }
}

// ---------------------------------------------------------------------------
// Per-edge: ex = exp(leaky_relu(ali[i]+alj[j])); atomic segment-sum into seg.
// (Softmax max-subtraction cancels algebraically; logits are O(1) here.)
// ex itself is NOT stored — it is recomputed in aggregate.
// ---------------------------------------------------------------------------
__global__ __launch_bounds__(256) void edge_seg(
    const int* __restrict__ src, const int* __restrict__ dst,
    const float4* __restrict__ ali4, const float4* __restrict__ alj4,
    float* __restrict__ seg, int E, int total)
{
    const int e = blockIdx.x * 256 + threadIdx.x;
    if (e >= total) return;
    int i, j;
    if (e < E) { i = src[e]; j = dst[e]; }
    else       { i = e - E;  j = i; }

    const float4 a  = ali4[i];
    const float4 bj = alj4[j];
    float l0 = a.x + bj.x, l1 = a.y + bj.y, l2 = a.z + bj.z, l3 = a.w + bj.w;
    l0 = l0 > 0.f ? l0 : 0.2f * l0;
    l1 = l1 > 0.f ? l1 : 0.2f * l1;
    l2 = l2 > 0.f ? l2 : 0.2f * l2;
    l3 = l3 > 0.f ? l3 : 0.2f * l3;
    atomicAdd(seg + i * 4 + 0, expf(l0));
    atomicAdd(seg + i * 4 + 1, expf(l1));
    atomicAdd(seg + i * 4 + 2, expf(l2));
    atomicAdd(seg + i * 4 + 3, expf(l3));
}

// ---------------------------------------------------------------------------
// out[e_i, col] += alpha(e, col/32) * h[e_j, col]
// alpha recomputed per-thread from L1-resident ali/alj/seg tables.
// one thread per (edge, col); 128 cols per edge.
// ---------------------------------------------------------------------------
__global__ __launch_bounds__(256) void aggregate(
    const int* __restrict__ src, const int* __restrict__ dst,
    const float* __restrict__ ali, const float* __restrict__ alj,
    const float* __restrict__ seg, const __hip_bfloat16* __restrict__ h,
    float* __restrict__ out, int E, long long totalThreads)
{
    const long long gid = (long long)blockIdx.x * 256 + threadIdx.x;
    if (gid >= totalThreads) return;
    const int e   = (int)(gid >> 7);
    const int col = (int)(gid & 127);
    const int hh  = col >> 5;
    int i, j;
    if (e < E) { i = src[e]; j = dst[e]; }
    else       { i = e - E;  j = i; }

    float l = ali[i * 4 + hh] + alj[j * 4 + hh];
    l = l > 0.f ? l : 0.2f * l;
    const float alpha = expf(l) / seg[i * 4 + hh];
    const float v = __bfloat162float(h[(size_t)j * HC + col]);
    atomicAdd(out + (size_t)i * HC + col, alpha * v);
}

// ---------------------------------------------------------------------------
// out = relu(out + bias)
// ---------------------------------------------------------------------------
__global__ __launch_bounds__(256) void epilogue(
    float* __restrict__ out, const float* __restrict__ bias, long long total)
{
    const long long gid = (long long)blockIdx.x * 256 + threadIdx.x;
    if (gid >= total) return;
    const int col = (int)(gid & 127);
    const float v = out[gid] + bias[col];
    out[gid] = v > 0.f ? v : 0.f;
}

extern "C" void kernel_launch(void* const* d_in, const int* in_sizes, int n_in,
                              void* d_out, int out_size, void* d_ws, size_t ws_size,
                              hipStream_t stream)
{
    const float* x    = (const float*)d_in[0];
    const int*   ei   = (const int*)d_in[1];     // harness passes integers as int32
    const float* W    = (const float*)d_in[2];
    const float* b    = (const float*)d_in[3];
    const float* att  = (const float*)d_in[4];
    const float* bias = (const float*)d_in[5];

    const int n     = in_sizes[0] / DIN;   // 50000
    const int E     = in_sizes[1] / 2;     // 800000
    const int total = E + n;               // edges incl. self-loops

    const int* src = ei;        // e_i (segment index)
    const int* dst = ei + E;    // e_j (gather index)

    // workspace layout (15.2 MB total):
    //   h   : n*128 bf16   = 12.8 MB
    //   ali : n*4 fp32     = 0.8 MB
    //   alj : n*4 fp32     = 0.8 MB
    //   seg : n*4 fp32     = 0.8 MB
    __hip_bfloat16* h = (__hip_bfloat16*)d_ws;
    float* ali = (float*)((char*)d_ws + (size_t)n * HC * sizeof(__hip_bfloat16));
    float* alj = ali + (size_t)n * NH;
    float* seg = alj + (size_t)n * NH;

    float* out = (float*)d_out;

    hipMemsetAsync(out, 0, (size_t)n * HC * sizeof(float), stream);
    hipMemsetAsync(seg, 0, (size_t)n * NH * sizeof(float), stream);

    linear_fused<<<512, 256, 0, stream>>>(x, W, b, att, h, ali, alj, n);

    const int eb = (total + 255) / 256;
    edge_seg<<<eb, 256, 0, stream>>>(src, dst, (const float4*)ali,
                                     (const float4*)alj, seg, E, total);

    const long long aggT = (long long)total * HC;
    aggregate<<<(int)((aggT + 255) / 256), 256, 0, stream>>>(
        src, dst, ali, alj, seg, h, out, E, aggT);

    const long long oT = (long long)n * HC;
    epilogue<<<(int)((oT + 255) / 256), 256, 0, stream>>>(out, bias, oT);
}

// Round 4
// 330.833 us; speedup vs baseline: 2.0291x; 2.0291x over previous
//
#include <hip/hip_runtime.h>
#include <hip/hip_bf16.h>

#define DIN 128
#define HC  128
#define NH  4

typedef __attribute__((ext_vector_type(8))) short short8;
typedef __attribute__((ext_vector_type(4))) float floatx4;

__device__ inline short f2bf_bits(float f) {
    __hip_bfloat16 t = __float2bfloat16(f);
    return *reinterpret_cast<short*>(&t);
}
__device__ inline float bfbits2f(unsigned short u) {
    unsigned int v = ((unsigned int)u) << 16;
    union { unsigned int i; float f; } c; c.i = v; return c.f;
}

// ---------------------------------------------------------------------------
// wa[k*8+o]: o<4 -> sum_c W[k][o*32+c]*att[o*64+c]   (a_i part)
//            o>=4 -> sum_c W[k][(o-4)*32+c]*att[(o-4)*64+32+c]  (a_j part)
// wa[1024+o]: same dot with b_lin (constant terms).
// ---------------------------------------------------------------------------
__global__ __launch_bounds__(256) void compute_wa(
    const float* __restrict__ W, const float* __restrict__ b,
    const float* __restrict__ att, float* __restrict__ wa)
{
    for (int idx = threadIdx.x; idx < DIN * 8; idx += 256) {
        const int k = idx >> 3, o = idx & 7;
        const int hh = o & 3, jo = (o >> 2) * 32;
        float s = 0.f;
        #pragma unroll
        for (int c = 0; c < 32; ++c)
            s = fmaf(W[k * HC + hh * 32 + c], att[hh * 64 + jo + c], s);
        wa[idx] = s;
    }
    if (threadIdx.x < 8) {
        const int hh = threadIdx.x & 3, jo = (threadIdx.x >> 2) * 32;
        float s = 0.f;
        #pragma unroll
        for (int c = 0; c < 32; ++c)
            s = fmaf(b[hh * 32 + c], att[hh * 64 + jo + c], s);
        wa[DIN * 8 + threadIdx.x] = s;
    }
}

// ---------------------------------------------------------------------------
// ali[r,h] = x[r,:]·wa_i[:,h] + ci[h];  alj likewise. One wave per row.
// ---------------------------------------------------------------------------
__global__ __launch_bounds__(256) void node_logits(
    const float* __restrict__ x, const float* __restrict__ wa,
    float* __restrict__ ali, float* __restrict__ alj, int n)
{
    const int lane = threadIdx.x & 63;
    const int gw = (blockIdx.x * 256 + threadIdx.x) >> 6;
    const int nw = (gridDim.x * 256) >> 6;
    for (int r = gw; r < n; r += nw) {
        const float2 xv = *(const float2*)(x + (size_t)r * DIN + lane * 2);
        const float* w0 = wa + (lane * 2) * 8;
        const float* w1 = wa + (lane * 2 + 1) * 8;
        float p[8];
        #pragma unroll
        for (int o = 0; o < 8; ++o)
            p[o] = fmaf(xv.x, w0[o], xv.y * w1[o]);
        #pragma unroll
        for (int m = 1; m < 64; m <<= 1) {
            #pragma unroll
            for (int o = 0; o < 8; ++o) p[o] += __shfl_xor(p[o], m, 64);
        }
        if (lane < 8) {
            float v = 0.f;
            #pragma unroll
            for (int o = 0; o < 8; ++o) if (lane == o) v = p[o];
            v += wa[DIN * 8 + lane];
            if (lane < 4) ali[r * 4 + lane] = v;
            else          alj[r * 4 + lane - 4] = v;
        }
    }
}

// ---------------------------------------------------------------------------
// h = bf16(x @ W + b) via MFMA 16x16x32 bf16.
// Wt[col][k] (bf16, pad 136) in LDS; B-frags hoisted to registers; A-frags
// converted from fp32 x in-flight. One wave per 16-row tile (grid-stride).
// A: lane holds A[l%16][(l/16)*8+i]; B: B[(l/16)*8+i][l%16];
// D: D[(l/16)*4+reg][l%16]   (m89-verified C/D layout).
// ---------------------------------------------------------------------------
__global__ __launch_bounds__(256) void gemm_h(
    const float* __restrict__ x, const float* __restrict__ W,
    const float* __restrict__ b, __hip_bfloat16* __restrict__ h,
    int n, int ntiles)
{
    __shared__ __hip_bfloat16 Wt[DIN][136];   // 34.8 KB
    for (int idx = threadIdx.x; idx < DIN * HC; idx += 256) {
        const int k = idx >> 7, c = idx & 127;
        Wt[c][k] = __float2bfloat16(W[idx]);
    }
    __syncthreads();

    const int lane = threadIdx.x & 63;
    const int l15 = lane & 15, lg = lane >> 4;

    short8 bf[8][4];
    #pragma unroll
    for (int ct = 0; ct < 8; ++ct)
        #pragma unroll
        for (int ks = 0; ks < 4; ++ks)
            bf[ct][ks] = *(const short8*)(&Wt[ct * 16 + l15][ks * 32 + lg * 8]);

    float bc[8];
    #pragma unroll
    for (int ct = 0; ct < 8; ++ct) bc[ct] = b[ct * 16 + l15];

    const int gw = (blockIdx.x * 256 + threadIdx.x) >> 6;
    const int nw = (gridDim.x * 256) >> 6;
    for (int tile = gw; tile < ntiles; tile += nw) {
        int row = tile * 16 + l15;
        if (row >= n) row = n - 1;              // safe duplicate load
        floatx4 acc[8];
        #pragma unroll
        for (int ct = 0; ct < 8; ++ct) acc[ct] = (floatx4)0.f;

        #pragma unroll
        for (int ks = 0; ks < 4; ++ks) {
            const float4 f0 = *(const float4*)(x + (size_t)row * DIN + ks * 32 + lg * 8);
            const float4 f1 = *(const float4*)(x + (size_t)row * DIN + ks * 32 + lg * 8 + 4);
            short8 af;
            af[0] = f2bf_bits(f0.x); af[1] = f2bf_bits(f0.y);
            af[2] = f2bf_bits(f0.z); af[3] = f2bf_bits(f0.w);
            af[4] = f2bf_bits(f1.x); af[5] = f2bf_bits(f1.y);
            af[6] = f2bf_bits(f1.z); af[7] = f2bf_bits(f1.w);
            #pragma unroll
            for (int ct = 0; ct < 8; ++ct)
                acc[ct] = __builtin_amdgcn_mfma_f32_16x16x32_bf16(
                    af, bf[ct][ks], acc[ct], 0, 0, 0);
        }

        #pragma unroll
        for (int ct = 0; ct < 8; ++ct) {
            #pragma unroll
            for (int reg = 0; reg < 4; ++reg) {
                const int r = tile * 16 + lg * 4 + reg;
                if (r < n)
                    h[(size_t)r * HC + ct * 16 + l15] =
                        __float2bfloat16(acc[ct][reg] + bc[ct]);
            }
        }
    }
}

// ---------------------------------------------------------------------------
// CSR build: histogram -> single-block chunked scan -> scatter
// ---------------------------------------------------------------------------
__global__ __launch_bounds__(256) void count_deg(
    const int* __restrict__ src, int* __restrict__ deg, int E, int total)
{
    const int e = blockIdx.x * 256 + threadIdx.x;
    if (e >= total) return;
    const int i = (e < E) ? src[e] : (e - E);
    atomicAdd(&deg[i], 1);
}

__global__ __launch_bounds__(1024) void scan_deg(
    const int* __restrict__ deg, int* __restrict__ rowptr,
    int* __restrict__ cursor, int n)
{
    __shared__ int csum[1024];
    const int t = threadIdx.x;
    const int CH = (n + 1023) >> 10;
    const int s0 = t * CH;
    const int s1 = min(s0 + CH, n);
    int sum = 0;
    for (int k = s0; k < s1; ++k) sum += deg[k];
    csum[t] = sum;
    __syncthreads();
    for (int off = 1; off < 1024; off <<= 1) {
        const int u = (t >= off) ? csum[t - off] : 0;
        __syncthreads();
        csum[t] += u;
        __syncthreads();
    }
    int run = (t == 0) ? 0 : csum[t - 1];
    for (int k = s0; k < s1; ++k) {
        rowptr[k] = run; cursor[k] = run; run += deg[k];
    }
    if (t == 0) rowptr[n] = csum[1023];
}

__global__ __launch_bounds__(256) void scatter_edges(
    const int* __restrict__ src, const int* __restrict__ dst,
    int* __restrict__ cursor, int* __restrict__ csr, int E, int total)
{
    const int e = blockIdx.x * 256 + threadIdx.x;
    if (e >= total) return;
    int i, j;
    if (e < E) { i = src[e]; j = dst[e]; }
    else       { i = e - E;  j = i; }
    const int pos = atomicAdd(&cursor[i], 1);
    csr[pos] = j;
}

// ---------------------------------------------------------------------------
// One wave per node: phase 1 computes softmax denominator across neighbors;
// phase 2 accumulates out[i, 2 cols/lane] over neighbors. No atomics.
// bias + ReLU fused into the single coalesced store.
// ---------------------------------------------------------------------------
__global__ __launch_bounds__(256) void aggregate_csr(
    const int* __restrict__ rowptr, const int* __restrict__ csr,
    const float* __restrict__ ali, const float* __restrict__ alj,
    const __hip_bfloat16* __restrict__ h, const float* __restrict__ bias,
    float* __restrict__ out, int n)
{
    const int lane = threadIdx.x & 63;
    const int hh   = lane >> 4;                 // head of cols {2*lane, 2*lane+1}
    const int gw = (blockIdx.x * 256 + threadIdx.x) >> 6;
    const int nw = (gridDim.x * 256) >> 6;
    const unsigned short* hu = (const unsigned short*)h;

    for (int i = gw; i < n; i += nw) {
        const int rs = rowptr[i], re = rowptr[i + 1];
        const float4 a4 = *(const float4*)(ali + (size_t)i * 4);

        // phase 1: segment denominator (all 4 heads)
        float s0 = 0.f, s1 = 0.f, s2 = 0.f, s3 = 0.f;
        for (int t = rs + lane; t < re; t += 64) {
            const int j = csr[t];
            const float4 l4 = *(const float4*)(alj + (size_t)j * 4);
            float l0 = a4.x + l4.x, l1 = a4.y + l4.y;
            float l2 = a4.z + l4.z, l3 = a4.w + l4.w;
            l0 = l0 > 0.f ? l0 : 0.2f * l0;
            l1 = l1 > 0.f ? l1 : 0.2f * l1;
            l2 = l2 > 0.f ? l2 : 0.2f * l2;
            l3 = l3 > 0.f ? l3 : 0.2f * l3;
            s0 += __expf(l0); s1 += __expf(l1);
            s2 += __expf(l2); s3 += __expf(l3);
        }
        #pragma unroll
        for (int m = 1; m < 64; m <<= 1) {
            s0 += __shfl_xor(s0, m, 64);
            s1 += __shfl_xor(s1, m, 64);
            s2 += __shfl_xor(s2, m, 64);
            s3 += __shfl_xor(s3, m, 64);
        }
        float aii, segh;
        if      (hh == 0) { aii = a4.x; segh = s0; }
        else if (hh == 1) { aii = a4.y; segh = s1; }
        else if (hh == 2) { aii = a4.z; segh = s2; }
        else              { aii = a4.w; segh = s3; }
        const float inv = 1.0f / segh;

        // phase 2: accumulate 2 cols per lane over neighbors
        float acc0 = 0.f, acc1 = 0.f;
        int jn = csr[rs];
        for (int t = rs; t < re; ++t) {
            const int j = jn;
            if (t + 1 < re) jn = csr[t + 1];
            float l = aii + alj[(size_t)j * 4 + hh];
            l = l > 0.f ? l : 0.2f * l;
            const float w = __expf(l) * inv;
            const ushort2 u = *(const ushort2*)(hu + (size_t)j * HC + lane * 2);
            acc0 = fmaf(w, bfbits2f(u.x), acc0);
            acc1 = fmaf(w, bfbits2f(u.y), acc1);
        }
        const float b0 = bias[lane * 2], b1 = bias[lane * 2 + 1];
        float o0 = acc0 + b0, o1 = acc1 + b1;
        float2 ov;
        ov.x = o0 > 0.f ? o0 : 0.f;
        ov.y = o1 > 0.f ? o1 : 0.f;
        *(float2*)(out + (size_t)i * HC + lane * 2) = ov;
    }
}

extern "C" void kernel_launch(void* const* d_in, const int* in_sizes, int n_in,
                              void* d_out, int out_size, void* d_ws, size_t ws_size,
                              hipStream_t stream)
{
    const float* x    = (const float*)d_in[0];
    const int*   ei   = (const int*)d_in[1];     // int32 (harness convention)
    const float* W    = (const float*)d_in[2];
    const float* b    = (const float*)d_in[3];
    const float* att  = (const float*)d_in[4];
    const float* bias = (const float*)d_in[5];

    const int n     = in_sizes[0] / DIN;   // 50000
    const int E     = in_sizes[1] / 2;     // 800000
    const int total = E + n;

    const int* src = ei;        // e_i (segment index)
    const int* dst = ei + E;    // e_j (gather index)

    // workspace layout (~18.3 MB), 256B-aligned slices
    char* ws = (char*)d_ws;
    size_t off = 0;
    auto take = [&](size_t bytes) {
        char* p = ws + off;
        off += (bytes + 255) & ~(size_t)255;
        return p;
    };
    __hip_bfloat16* h   = (__hip_bfloat16*)take((size_t)n * HC * 2);
    float* ali    = (float*)take((size_t)n * NH * 4);
    float* alj    = (float*)take((size_t)n * NH * 4);
    float* wa     = (float*)take((DIN * 8 + 8) * 4);
    int*   rowptr = (int*)take((size_t)(n + 1) * 4);
    int*   cursor = (int*)take((size_t)n * 4);
    int*   deg    = (int*)take((size_t)n * 4);
    int*   csr    = (int*)take((size_t)total * 4);

    float* out = (float*)d_out;

    hipMemsetAsync(deg, 0, (size_t)n * 4, stream);

    compute_wa<<<1, 256, 0, stream>>>(W, b, att, wa);

    const int nodeBlocks = (n + 3) / 4;            // 4 waves/block, 1 node/wave
    node_logits<<<nodeBlocks, 256, 0, stream>>>(x, wa, ali, alj, n);

    const int ntiles = (n + 15) / 16;
    gemm_h<<<256, 256, 0, stream>>>(x, W, b, h, n, ntiles);

    const int eb = (total + 255) / 256;
    count_deg<<<eb, 256, 0, stream>>>(src, deg, E, total);
    scan_deg<<<1, 1024, 0, stream>>>(deg, rowptr, cursor, n);
    scatter_edges<<<eb, 256, 0, stream>>>(src, dst, cursor, csr, E, total);

    aggregate_csr<<<nodeBlocks, 256, 0, stream>>>(rowptr, csr, ali, alj, h,
                                                  bias, out, n);
}

// Round 5
// 224.708 us; speedup vs baseline: 2.9874x; 1.4723x over previous
//
#include <hip/hip_runtime.h>
#include <hip/hip_bf16.h>

#define DIN 128
#define HC  128
#define NH  4

typedef __attribute__((ext_vector_type(8))) short short8;
typedef __attribute__((ext_vector_type(4))) float floatx4;

__device__ inline short f2bf_bits(float f) {
    __hip_bfloat16 t = __float2bfloat16(f);
    return *reinterpret_cast<short*>(&t);
}
__device__ inline float bfbits2f(unsigned short u) {
    union { unsigned int i; float f; } c; c.i = ((unsigned int)u) << 16; return c.f;
}

// ---------------------------------------------------------------------------
// wa[k*8+o]: o<4 -> sum_c W[k][o*32+c]*att[o*64+c]            (a_i part)
//            o>=4 -> sum_c W[k][(o-4)*32+c]*att[(o-4)*64+32+c] (a_j part)
// wa[1024+o]: same dot with b_lin (constant terms).
// ---------------------------------------------------------------------------
__global__ __launch_bounds__(256) void compute_wa(
    const float* __restrict__ W, const float* __restrict__ b,
    const float* __restrict__ att, float* __restrict__ wa)
{
    for (int idx = threadIdx.x; idx < DIN * 8; idx += 256) {
        const int k = idx >> 3, o = idx & 7;
        const int hh = o & 3, jo = (o >> 2) * 32;
        float s = 0.f;
        #pragma unroll
        for (int c = 0; c < 32; ++c)
            s = fmaf(W[k * HC + hh * 32 + c], att[hh * 64 + jo + c], s);
        wa[idx] = s;
    }
    if (threadIdx.x < 8) {
        const int hh = threadIdx.x & 3, jo = (threadIdx.x >> 2) * 32;
        float s = 0.f;
        #pragma unroll
        for (int c = 0; c < 32; ++c)
            s = fmaf(b[hh * 32 + c], att[hh * 64 + jo + c], s);
        wa[DIN * 8 + threadIdx.x] = s;
    }
}

// ---------------------------------------------------------------------------
// ali[r,h] = x[r,:]·wa_i[:,h] + ci[h];  alj likewise. One wave per row.
// ---------------------------------------------------------------------------
__global__ __launch_bounds__(256) void node_logits(
    const float* __restrict__ x, const float* __restrict__ wa,
    float* __restrict__ ali, float* __restrict__ alj, int n)
{
    const int lane = threadIdx.x & 63;
    const int gw = (blockIdx.x * 256 + threadIdx.x) >> 6;
    const int nw = (gridDim.x * 256) >> 6;
    for (int r = gw; r < n; r += nw) {
        const float2 xv = *(const float2*)(x + (size_t)r * DIN + lane * 2);
        const float* w0 = wa + (lane * 2) * 8;
        const float* w1 = wa + (lane * 2 + 1) * 8;
        float p[8];
        #pragma unroll
        for (int o = 0; o < 8; ++o)
            p[o] = fmaf(xv.x, w0[o], xv.y * w1[o]);
        #pragma unroll
        for (int m = 1; m < 64; m <<= 1) {
            #pragma unroll
            for (int o = 0; o < 8; ++o) p[o] += __shfl_xor(p[o], m, 64);
        }
        if (lane < 8) {
            float v = 0.f;
            #pragma unroll
            for (int o = 0; o < 8; ++o) if (lane == o) v = p[o];
            v += wa[DIN * 8 + lane];
            if (lane < 4) ali[r * 4 + lane] = v;
            else          alj[r * 4 + lane - 4] = v;
        }
    }
}

// ---------------------------------------------------------------------------
// h = bf16(x @ W + b) via MFMA 16x16x32 bf16.
// Wt[col][k] (bf16, pad 136) in LDS; B-frags hoisted to registers; A-frags
// converted from fp32 x in-flight. One wave per 16-row tile (grid-stride).
// ---------------------------------------------------------------------------
__global__ __launch_bounds__(256) void gemm_h(
    const float* __restrict__ x, const float* __restrict__ W,
    const float* __restrict__ b, __hip_bfloat16* __restrict__ h,
    int n, int ntiles)
{
    __shared__ __hip_bfloat16 Wt[DIN][136];
    for (int idx = threadIdx.x; idx < DIN * HC; idx += 256) {
        const int k = idx >> 7, c = idx & 127;
        Wt[c][k] = __float2bfloat16(W[idx]);
    }
    __syncthreads();

    const int lane = threadIdx.x & 63;
    const int l15 = lane & 15, lg = lane >> 4;

    short8 bf[8][4];
    #pragma unroll
    for (int ct = 0; ct < 8; ++ct)
        #pragma unroll
        for (int ks = 0; ks < 4; ++ks)
            bf[ct][ks] = *(const short8*)(&Wt[ct * 16 + l15][ks * 32 + lg * 8]);

    float bc[8];
    #pragma unroll
    for (int ct = 0; ct < 8; ++ct) bc[ct] = b[ct * 16 + l15];

    const int gw = (blockIdx.x * 256 + threadIdx.x) >> 6;
    const int nw = (gridDim.x * 256) >> 6;
    for (int tile = gw; tile < ntiles; tile += nw) {
        int row = tile * 16 + l15;
        if (row >= n) row = n - 1;              // safe duplicate load
        floatx4 acc[8];
        #pragma unroll
        for (int ct = 0; ct < 8; ++ct) acc[ct] = (floatx4)0.f;

        #pragma unroll
        for (int ks = 0; ks < 4; ++ks) {
            const float4 f0 = *(const float4*)(x + (size_t)row * DIN + ks * 32 + lg * 8);
            const float4 f1 = *(const float4*)(x + (size_t)row * DIN + ks * 32 + lg * 8 + 4);
            short8 af;
            af[0] = f2bf_bits(f0.x); af[1] = f2bf_bits(f0.y);
            af[2] = f2bf_bits(f0.z); af[3] = f2bf_bits(f0.w);
            af[4] = f2bf_bits(f1.x); af[5] = f2bf_bits(f1.y);
            af[6] = f2bf_bits(f1.z); af[7] = f2bf_bits(f1.w);
            #pragma unroll
            for (int ct = 0; ct < 8; ++ct)
                acc[ct] = __builtin_amdgcn_mfma_f32_16x16x32_bf16(
                    af, bf[ct][ks], acc[ct], 0, 0, 0);
        }

        #pragma unroll
        for (int ct = 0; ct < 8; ++ct) {
            #pragma unroll
            for (int reg = 0; reg < 4; ++reg) {
                const int r = tile * 16 + lg * 4 + reg;
                if (r < n)
                    h[(size_t)r * HC + ct * 16 + l15] =
                        __float2bfloat16(acc[ct][reg] + bc[ct]);
            }
        }
    }
}

// ---------------------------------------------------------------------------
// CSR build: histogram -> hierarchical scan (3 small kernels) -> scatter
// ---------------------------------------------------------------------------
__global__ __launch_bounds__(256) void count_deg(
    const int* __restrict__ src, int* __restrict__ deg, int E, int total)
{
    const int e = blockIdx.x * 256 + threadIdx.x;
    if (e >= total) return;
    const int i = (e < E) ? src[e] : (e - E);
    atomicAdd(&deg[i], 1);
}

// intra-block exclusive scan of deg -> rowptr; per-block sums -> bsum
__global__ __launch_bounds__(256) void scan1(
    const int* __restrict__ deg, int* __restrict__ rowptr,
    int* __restrict__ bsum, int n)
{
    __shared__ int sh[256];
    const int t = threadIdx.x;
    const int i = blockIdx.x * 256 + t;
    const int v = (i < n) ? deg[i] : 0;
    sh[t] = v;
    __syncthreads();
    #pragma unroll
    for (int off = 1; off < 256; off <<= 1) {
        const int u = (t >= off) ? sh[t - off] : 0;
        __syncthreads();
        sh[t] += u;
        __syncthreads();
    }
    if (i < n) rowptr[i] = sh[t] - v;       // exclusive within block
    if (t == 255) bsum[blockIdx.x] = sh[255];
}

// single block: exclusive scan of block sums -> boff; grand total -> rowptr[n]
__global__ __launch_bounds__(1024) void scan2(
    const int* __restrict__ bsum, int* __restrict__ boff,
    int* __restrict__ rowptr, int nb, int n)
{
    __shared__ int sh[1024];
    const int t = threadIdx.x;
    const int v = (t < nb) ? bsum[t] : 0;
    sh[t] = v;
    __syncthreads();
    #pragma unroll
    for (int off = 1; off < 1024; off <<= 1) {
        const int u = (t >= off) ? sh[t - off] : 0;
        __syncthreads();
        sh[t] += u;
        __syncthreads();
    }
    if (t < nb) boff[t] = sh[t] - v;
    if (t == nb - 1) rowptr[n] = sh[t];
}

// rowptr += block offset; cursor = rowptr
__global__ __launch_bounds__(256) void scan3(
    int* __restrict__ rowptr, int* __restrict__ cursor,
    const int* __restrict__ boff, int n)
{
    const int i = blockIdx.x * 256 + threadIdx.x;
    if (i >= n) return;
    const int r = rowptr[i] + boff[blockIdx.x];
    rowptr[i] = r;
    cursor[i] = r;
}

__global__ __launch_bounds__(256) void scatter_edges(
    const int* __restrict__ src, const int* __restrict__ dst,
    int* __restrict__ cursor, int* __restrict__ csr, int E, int total)
{
    const int e = blockIdx.x * 256 + threadIdx.x;
    if (e >= total) return;
    int i, j;
    if (e < E) { i = src[e]; j = dst[e]; }
    else       { i = e - E;  j = i; }
    const int pos = atomicAdd(&cursor[i], 1);
    csr[pos] = j;
}

// ---------------------------------------------------------------------------
// One wave per node, SINGLE pass over neighbors: each lane owns 2 output
// cols of head hh = lane>>4 and accumulates both the un-normalized weighted
// sum and the softmax denominator for its head (identical serial order for
// all lanes of a head -> deterministic). One normalize + bias + ReLU at end.
// ---------------------------------------------------------------------------
__global__ __launch_bounds__(256) void aggregate_csr(
    const int* __restrict__ rowptr, const int* __restrict__ csr,
    const float* __restrict__ ali, const float* __restrict__ alj,
    const __hip_bfloat16* __restrict__ h, const float* __restrict__ bias,
    float* __restrict__ out, int n)
{
    const int lane = threadIdx.x & 63;
    const int hh   = lane >> 4;
    const int gw = (blockIdx.x * 256 + threadIdx.x) >> 6;
    const int nw = (gridDim.x * 256) >> 6;
    const unsigned short* hu = (const unsigned short*)h;

    for (int i = gw; i < n; i += nw) {
        const int rs = rowptr[i], re = rowptr[i + 1];
        const float aii = ali[(size_t)i * 4 + hh];

        float acc0 = 0.f, acc1 = 0.f, s = 0.f;
        int jn = csr[rs];
        for (int t = rs; t < re; ++t) {
            const int j = jn;
            if (t + 1 < re) jn = csr[t + 1];
            float l = aii + alj[(size_t)j * 4 + hh];
            l = l > 0.f ? l : 0.2f * l;
            const float ex = __expf(l);
            s += ex;
            const ushort2 u = *(const ushort2*)(hu + (size_t)j * HC + lane * 2);
            acc0 = fmaf(ex, bfbits2f(u.x), acc0);
            acc1 = fmaf(ex, bfbits2f(u.y), acc1);
        }
        const float inv = 1.0f / s;
        float o0 = fmaf(acc0, inv, bias[lane * 2]);
        float o1 = fmaf(acc1, inv, bias[lane * 2 + 1]);
        float2 ov;
        ov.x = o0 > 0.f ? o0 : 0.f;
        ov.y = o1 > 0.f ? o1 : 0.f;
        *(float2*)(out + (size_t)i * HC + lane * 2) = ov;
    }
}

extern "C" void kernel_launch(void* const* d_in, const int* in_sizes, int n_in,
                              void* d_out, int out_size, void* d_ws, size_t ws_size,
                              hipStream_t stream)
{
    const float* x    = (const float*)d_in[0];
    const int*   ei   = (const int*)d_in[1];     // int32 (harness convention)
    const float* W    = (const float*)d_in[2];
    const float* b    = (const float*)d_in[3];
    const float* att  = (const float*)d_in[4];
    const float* bias = (const float*)d_in[5];

    const int n     = in_sizes[0] / DIN;   // 50000
    const int E     = in_sizes[1] / 2;     // 800000
    const int total = E + n;

    const int* src = ei;        // e_i (segment index)
    const int* dst = ei + E;    // e_j (gather index)

    // workspace layout (~18.3 MB), 256B-aligned slices
    char* ws = (char*)d_ws;
    size_t off = 0;
    auto take = [&](size_t bytes) {
        char* p = ws + off;
        off += (bytes + 255) & ~(size_t)255;
        return p;
    };
    const int nb = (n + 255) / 256;                     // scan blocks (196)
    __hip_bfloat16* h   = (__hip_bfloat16*)take((size_t)n * HC * 2);
    float* ali    = (float*)take((size_t)n * NH * 4);
    float* alj    = (float*)take((size_t)n * NH * 4);
    float* wa     = (float*)take((DIN * 8 + 8) * 4);
    int*   rowptr = (int*)take((size_t)(n + 1) * 4);
    int*   cursor = (int*)take((size_t)n * 4);
    int*   deg    = (int*)take((size_t)n * 4);
    int*   bsum   = (int*)take((size_t)nb * 4);
    int*   boff   = (int*)take((size_t)nb * 4);
    int*   csr    = (int*)take((size_t)total * 4);

    float* out = (float*)d_out;

    hipMemsetAsync(deg, 0, (size_t)n * 4, stream);

    compute_wa<<<1, 256, 0, stream>>>(W, b, att, wa);

    const int nodeBlocks = (n + 3) / 4;            // 4 waves/block, 1 node/wave
    node_logits<<<nodeBlocks, 256, 0, stream>>>(x, wa, ali, alj, n);

    const int ntiles = (n + 15) / 16;
    gemm_h<<<256, 256, 0, stream>>>(x, W, b, h, n, ntiles);

    const int eb = (total + 255) / 256;
    count_deg<<<eb, 256, 0, stream>>>(src, deg, E, total);
    scan1<<<nb, 256, 0, stream>>>(deg, rowptr, bsum, n);
    scan2<<<1, 1024, 0, stream>>>(bsum, boff, rowptr, nb, n);
    scan3<<<nb, 256, 0, stream>>>(rowptr, cursor, boff, n);
    scatter_edges<<<eb, 256, 0, stream>>>(src, dst, cursor, csr, E, total);

    aggregate_csr<<<nodeBlocks, 256, 0, stream>>>(rowptr, csr, ali, alj, h,
                                                  bias, out, n);
}

// Round 6
// 159.532 us; speedup vs baseline: 4.2079x; 1.4086x over previous
//
#include <hip/hip_runtime.h>
#include <hip/hip_bf16.h>

#define DIN 128
#define HC  128
#define NH  4

typedef __attribute__((ext_vector_type(8))) short short8;
typedef __attribute__((ext_vector_type(4))) float floatx4;

__device__ inline short f2bf_bits(float f) {
    __hip_bfloat16 t = __float2bfloat16(f);
    return *reinterpret_cast<short*>(&t);
}
__device__ inline float bfbits2f(unsigned short u) {
    union { unsigned int i; float f; } c; c.i = ((unsigned int)u) << 16; return c.f;
}

// ---------------------------------------------------------------------------
// wa[k*8+o]: o<4 -> sum_c W[k][o*32+c]*att[o*64+c]            (a_i part)
//            o>=4 -> sum_c W[k][(o-4)*32+c]*att[(o-4)*64+32+c] (a_j part)
// wa[1024+o]: same dot with b_lin (constant terms).
// ---------------------------------------------------------------------------
__global__ __launch_bounds__(256) void compute_wa(
    const float* __restrict__ W, const float* __restrict__ b,
    const float* __restrict__ att, float* __restrict__ wa)
{
    for (int idx = threadIdx.x; idx < DIN * 8; idx += 256) {
        const int k = idx >> 3, o = idx & 7;
        const int hh = o & 3, jo = (o >> 2) * 32;
        float s = 0.f;
        #pragma unroll
        for (int c = 0; c < 32; ++c)
            s = fmaf(W[k * HC + hh * 32 + c], att[hh * 64 + jo + c], s);
        wa[idx] = s;
    }
    if (threadIdx.x < 8) {
        const int hh = threadIdx.x & 3, jo = (threadIdx.x >> 2) * 32;
        float s = 0.f;
        #pragma unroll
        for (int c = 0; c < 32; ++c)
            s = fmaf(b[hh * 32 + c], att[hh * 64 + jo + c], s);
        wa[DIN * 8 + threadIdx.x] = s;
    }
}

// ---------------------------------------------------------------------------
// ali[r,h] = x[r,:]·wa_i[:,h] + ci[h];  alj likewise. One wave per row.
// ---------------------------------------------------------------------------
__global__ __launch_bounds__(256) void node_logits(
    const float* __restrict__ x, const float* __restrict__ wa,
    float* __restrict__ ali, float* __restrict__ alj, int n)
{
    const int lane = threadIdx.x & 63;
    const int gw = (blockIdx.x * 256 + threadIdx.x) >> 6;
    const int nw = (gridDim.x * 256) >> 6;
    for (int r = gw; r < n; r += nw) {
        const float2 xv = *(const float2*)(x + (size_t)r * DIN + lane * 2);
        const float* w0 = wa + (lane * 2) * 8;
        const float* w1 = wa + (lane * 2 + 1) * 8;
        float p[8];
        #pragma unroll
        for (int o = 0; o < 8; ++o)
            p[o] = fmaf(xv.x, w0[o], xv.y * w1[o]);
        #pragma unroll
        for (int m = 1; m < 64; m <<= 1) {
            #pragma unroll
            for (int o = 0; o < 8; ++o) p[o] += __shfl_xor(p[o], m, 64);
        }
        if (lane < 8) {
            float v = 0.f;
            #pragma unroll
            for (int o = 0; o < 8; ++o) if (lane == o) v = p[o];
            v += wa[DIN * 8 + lane];
            if (lane < 4) ali[r * 4 + lane] = v;
            else          alj[r * 4 + lane - 4] = v;
        }
    }
}

// ---------------------------------------------------------------------------
// h = bf16(x @ W + b) via MFMA 16x16x32 bf16.
// Wt[col][k] (bf16, pad 136) in LDS; B-frags hoisted to registers; A-frags
// converted from fp32 x in-flight. One wave per 16-row tile (grid-stride).
// ---------------------------------------------------------------------------
__global__ __launch_bounds__(256) void gemm_h(
    const float* __restrict__ x, const float* __restrict__ W,
    const float* __restrict__ b, __hip_bfloat16* __restrict__ h,
    int n, int ntiles)
{
    __shared__ __hip_bfloat16 Wt[DIN][136];
    for (int idx = threadIdx.x; idx < DIN * HC; idx += 256) {
        const int k = idx >> 7, c = idx & 127;
        Wt[c][k] = __float2bfloat16(W[idx]);
    }
    __syncthreads();

    const int lane = threadIdx.x & 63;
    const int l15 = lane & 15, lg = lane >> 4;

    short8 bf[8][4];
    #pragma unroll
    for (int ct = 0; ct < 8; ++ct)
        #pragma unroll
        for (int ks = 0; ks < 4; ++ks)
            bf[ct][ks] = *(const short8*)(&Wt[ct * 16 + l15][ks * 32 + lg * 8]);

    float bc[8];
    #pragma unroll
    for (int ct = 0; ct < 8; ++ct) bc[ct] = b[ct * 16 + l15];

    const int gw = (blockIdx.x * 256 + threadIdx.x) >> 6;
    const int nw = (gridDim.x * 256) >> 6;
    for (int tile = gw; tile < ntiles; tile += nw) {
        int row = tile * 16 + l15;
        if (row >= n) row = n - 1;              // safe duplicate load
        floatx4 acc[8];
        #pragma unroll
        for (int ct = 0; ct < 8; ++ct) acc[ct] = (floatx4)0.f;

        #pragma unroll
        for (int ks = 0; ks < 4; ++ks) {
            const float4 f0 = *(const float4*)(x + (size_t)row * DIN + ks * 32 + lg * 8);
            const float4 f1 = *(const float4*)(x + (size_t)row * DIN + ks * 32 + lg * 8 + 4);
            short8 af;
            af[0] = f2bf_bits(f0.x); af[1] = f2bf_bits(f0.y);
            af[2] = f2bf_bits(f0.z); af[3] = f2bf_bits(f0.w);
            af[4] = f2bf_bits(f1.x); af[5] = f2bf_bits(f1.y);
            af[6] = f2bf_bits(f1.z); af[7] = f2bf_bits(f1.w);
            #pragma unroll
            for (int ct = 0; ct < 8; ++ct)
                acc[ct] = __builtin_amdgcn_mfma_f32_16x16x32_bf16(
                    af, bf[ct][ks], acc[ct], 0, 0, 0);
        }

        #pragma unroll
        for (int ct = 0; ct < 8; ++ct) {
            #pragma unroll
            for (int reg = 0; reg < 4; ++reg) {
                const int r = tile * 16 + lg * 4 + reg;
                if (r < n)
                    h[(size_t)r * HC + ct * 16 + l15] =
                        __float2bfloat16(acc[ct][reg] + bc[ct]);
            }
        }
    }
}

// ---------------------------------------------------------------------------
// CSR build: histogram (+per-edge rank) -> hierarchical scan -> atomic-free
// scatter. csr/rank are ushort (n < 2^16, deg_max << 2^16).
// ---------------------------------------------------------------------------
__global__ __launch_bounds__(256) void count_deg(
    const int* __restrict__ src, int* __restrict__ deg,
    unsigned short* __restrict__ rank, int E, int total)
{
    const int e = blockIdx.x * 256 + threadIdx.x;
    if (e >= total) return;
    const int i = (e < E) ? src[e] : (e - E);
    rank[e] = (unsigned short)atomicAdd(&deg[i], 1);
}

// intra-block exclusive scan of deg -> rowptr; per-block sums -> bsum
__global__ __launch_bounds__(256) void scan1(
    const int* __restrict__ deg, int* __restrict__ rowptr,
    int* __restrict__ bsum, int n)
{
    __shared__ int sh[256];
    const int t = threadIdx.x;
    const int i = blockIdx.x * 256 + t;
    const int v = (i < n) ? deg[i] : 0;
    sh[t] = v;
    __syncthreads();
    #pragma unroll
    for (int off = 1; off < 256; off <<= 1) {
        const int u = (t >= off) ? sh[t - off] : 0;
        __syncthreads();
        sh[t] += u;
        __syncthreads();
    }
    if (i < n) rowptr[i] = sh[t] - v;       // exclusive within block
    if (t == 255) bsum[blockIdx.x] = sh[255];
}

// single block: exclusive scan of block sums -> boff; grand total -> rowptr[n]
__global__ __launch_bounds__(1024) void scan2(
    const int* __restrict__ bsum, int* __restrict__ boff,
    int* __restrict__ rowptr, int nb, int n)
{
    __shared__ int sh[1024];
    const int t = threadIdx.x;
    const int v = (t < nb) ? bsum[t] : 0;
    sh[t] = v;
    __syncthreads();
    #pragma unroll
    for (int off = 1; off < 1024; off <<= 1) {
        const int u = (t >= off) ? sh[t - off] : 0;
        __syncthreads();
        sh[t] += u;
        __syncthreads();
    }
    if (t < nb) boff[t] = sh[t] - v;
    if (t == nb - 1) rowptr[n] = sh[t];
}

// rowptr += block offset
__global__ __launch_bounds__(256) void scan3(
    int* __restrict__ rowptr, const int* __restrict__ boff, int n)
{
    const int i = blockIdx.x * 256 + threadIdx.x;
    if (i >= n) return;
    rowptr[i] += boff[blockIdx.x];
}

// atomic-free scatter: pos = rowptr[i] + rank[e]
__global__ __launch_bounds__(256) void scatter_edges(
    const int* __restrict__ src, const int* __restrict__ dst,
    const unsigned short* __restrict__ rank, const int* __restrict__ rowptr,
    unsigned short* __restrict__ csr, int E, int total)
{
    const int e = blockIdx.x * 256 + threadIdx.x;
    if (e >= total) return;
    int i, j;
    if (e < E) { i = src[e]; j = dst[e]; }
    else       { i = e - E;  j = i; }
    csr[rowptr[i] + (int)rank[e]] = (unsigned short)j;
}

// ---------------------------------------------------------------------------
// One wave per node, single pass, unroll-4 over neighbors (4 independent
// h-row loads in flight). Lane owns 2 output cols of head hh = lane>>4;
// accumulates weighted sum + softmax denominator in the same serial order
// as the scalar loop. Normalize + bias + ReLU fused into the single store.
// ---------------------------------------------------------------------------
__global__ __launch_bounds__(256) void aggregate_csr(
    const int* __restrict__ rowptr, const unsigned short* __restrict__ csr,
    const float* __restrict__ ali, const float* __restrict__ alj,
    const __hip_bfloat16* __restrict__ h, const float* __restrict__ bias,
    float* __restrict__ out, int n)
{
    const int lane = threadIdx.x & 63;
    const int hh   = lane >> 4;
    const int gw = (blockIdx.x * 256 + threadIdx.x) >> 6;
    const int nw = (gridDim.x * 256) >> 6;
    const unsigned short* hu = (const unsigned short*)h;

    for (int i = gw; i < n; i += nw) {
        const int rs = rowptr[i], re = rowptr[i + 1];
        const float aii = ali[(size_t)i * 4 + hh];

        float acc0 = 0.f, acc1 = 0.f, s = 0.f;
        int t = rs;
        for (; t + 4 <= re; t += 4) {
            int jj[4]; float ll[4]; ushort2 uu[4];
            #pragma unroll
            for (int q = 0; q < 4; ++q) jj[q] = csr[t + q];
            #pragma unroll
            for (int q = 0; q < 4; ++q) ll[q] = alj[(size_t)jj[q] * 4 + hh];
            #pragma unroll
            for (int q = 0; q < 4; ++q)
                uu[q] = *(const ushort2*)(hu + (size_t)jj[q] * HC + lane * 2);
            #pragma unroll
            for (int q = 0; q < 4; ++q) {
                float l = aii + ll[q];
                l = l > 0.f ? l : 0.2f * l;
                const float ex = __expf(l);
                s += ex;
                acc0 = fmaf(ex, bfbits2f(uu[q].x), acc0);
                acc1 = fmaf(ex, bfbits2f(uu[q].y), acc1);
            }
        }
        for (; t < re; ++t) {
            const int j = csr[t];
            float l = aii + alj[(size_t)j * 4 + hh];
            l = l > 0.f ? l : 0.2f * l;
            const float ex = __expf(l);
            s += ex;
            const ushort2 u = *(const ushort2*)(hu + (size_t)j * HC + lane * 2);
            acc0 = fmaf(ex, bfbits2f(u.x), acc0);
            acc1 = fmaf(ex, bfbits2f(u.y), acc1);
        }
        const float inv = 1.0f / s;
        float o0 = fmaf(acc0, inv, bias[lane * 2]);
        float o1 = fmaf(acc1, inv, bias[lane * 2 + 1]);
        float2 ov;
        ov.x = o0 > 0.f ? o0 : 0.f;
        ov.y = o1 > 0.f ? o1 : 0.f;
        *(float2*)(out + (size_t)i * HC + lane * 2) = ov;
    }
}

extern "C" void kernel_launch(void* const* d_in, const int* in_sizes, int n_in,
                              void* d_out, int out_size, void* d_ws, size_t ws_size,
                              hipStream_t stream)
{
    const float* x    = (const float*)d_in[0];
    const int*   ei   = (const int*)d_in[1];     // int32 (harness convention)
    const float* W    = (const float*)d_in[2];
    const float* b    = (const float*)d_in[3];
    const float* att  = (const float*)d_in[4];
    const float* bias = (const float*)d_in[5];

    const int n     = in_sizes[0] / DIN;   // 50000
    const int E     = in_sizes[1] / 2;     // 800000
    const int total = E + n;

    const int* src = ei;        // e_i (segment index)
    const int* dst = ei + E;    // e_j (gather index)

    // workspace layout (~18.1 MB), 256B-aligned slices
    char* ws = (char*)d_ws;
    size_t off = 0;
    auto take = [&](size_t bytes) {
        char* p = ws + off;
        off += (bytes + 255) & ~(size_t)255;
        return p;
    };
    const int nb = (n + 255) / 256;                     // scan blocks (196)
    __hip_bfloat16* h   = (__hip_bfloat16*)take((size_t)n * HC * 2);
    float* ali    = (float*)take((size_t)n * NH * 4);
    float* alj    = (float*)take((size_t)n * NH * 4);
    float* wa     = (float*)take((DIN * 8 + 8) * 4);
    int*   rowptr = (int*)take((size_t)(n + 1) * 4);
    int*   deg    = (int*)take((size_t)n * 4);
    int*   bsum   = (int*)take((size_t)nb * 4);
    int*   boff   = (int*)take((size_t)nb * 4);
    unsigned short* rank = (unsigned short*)take((size_t)total * 2);
    unsigned short* csr  = (unsigned short*)take((size_t)total * 2);

    float* out = (float*)d_out;

    hipMemsetAsync(deg, 0, (size_t)n * 4, stream);

    compute_wa<<<1, 256, 0, stream>>>(W, b, att, wa);

    const int nodeBlocks = (n + 3) / 4;            // 4 waves/block, 1 node/wave
    node_logits<<<nodeBlocks, 256, 0, stream>>>(x, wa, ali, alj, n);

    const int ntiles = (n + 15) / 16;
    gemm_h<<<256, 256, 0, stream>>>(x, W, b, h, n, ntiles);

    const int eb = (total + 255) / 256;
    count_deg<<<eb, 256, 0, stream>>>(src, deg, rank, E, total);
    scan1<<<nb, 256, 0, stream>>>(deg, rowptr, bsum, n);
    scan2<<<1, 1024, 0, stream>>>(bsum, boff, rowptr, nb, n);
    scan3<<<nb, 256, 0, stream>>>(rowptr, boff, n);
    scatter_edges<<<eb, 256, 0, stream>>>(src, dst, rank, rowptr, csr, E, total);

    aggregate_csr<<<nodeBlocks, 256, 0, stream>>>(rowptr, csr, ali, alj, h,
                                                  bias, out, n);
}

// Round 7
// 122.729 us; speedup vs baseline: 5.4698x; 1.2999x over previous
//
#include <hip/hip_runtime.h>
#include <hip/hip_bf16.h>

#define DIN 128
#define HC  128
#define NH  4

typedef __attribute__((ext_vector_type(8))) short short8;
typedef __attribute__((ext_vector_type(4))) float floatx4;

__device__ inline short f2bf_bits(float f) {
    __hip_bfloat16 t = __float2bfloat16(f);
    return *reinterpret_cast<short*>(&t);
}
__device__ inline float bfbits2f(unsigned short u) {
    union { unsigned int i; float f; } c; c.i = ((unsigned int)u) << 16; return c.f;
}

// ---------------------------------------------------------------------------
// h = bf16(x @ W + b) via MFMA 16x16x32 bf16, with FUSED per-node attention
// logits: ali[r,hd] = sum_c h[r,hd*32+c]*att[hd,c], alj likewise (att[...,32+c]).
// Head of output col (= ct*16+l15) is ct>>1, so per-lane partials need only
// 2 FMAs per head per reg; 4-step shfl_xor reduces over the 16-lane group.
// Wt[col][k] (bf16, pad 136) in LDS; B-frags hoisted to registers.
// ---------------------------------------------------------------------------
__global__ __launch_bounds__(256) void gemm_h(
    const float* __restrict__ x, const float* __restrict__ W,
    const float* __restrict__ b, const float* __restrict__ att,
    __hip_bfloat16* __restrict__ h, float* __restrict__ ali,
    float* __restrict__ alj, int n, int ntiles)
{
    __shared__ __hip_bfloat16 Wt[DIN][136];
    for (int idx = threadIdx.x; idx < DIN * HC; idx += 256) {
        const int k = idx >> 7, c = idx & 127;
        Wt[c][k] = __float2bfloat16(W[idx]);
    }
    __syncthreads();

    const int lane = threadIdx.x & 63;
    const int l15 = lane & 15, lg = lane >> 4;

    short8 bf[8][4];
    #pragma unroll
    for (int ct = 0; ct < 8; ++ct)
        #pragma unroll
        for (int ks = 0; ks < 4; ++ks)
            bf[ct][ks] = *(const short8*)(&Wt[ct * 16 + l15][ks * 32 + lg * 8]);

    float bc[8], ai_l[8], aj_l[8];
    #pragma unroll
    for (int ct = 0; ct < 8; ++ct) {
        bc[ct]   = b[ct * 16 + l15];
        ai_l[ct] = att[(ct >> 1) * 64 + (ct & 1) * 16 + l15];
        aj_l[ct] = att[(ct >> 1) * 64 + 32 + (ct & 1) * 16 + l15];
    }

    const int gw = (blockIdx.x * 256 + threadIdx.x) >> 6;
    const int nw = (gridDim.x * 256) >> 6;
    for (int tile = gw; tile < ntiles; tile += nw) {
        int row = tile * 16 + l15;
        if (row >= n) row = n - 1;              // safe duplicate load
        floatx4 acc[8];
        #pragma unroll
        for (int ct = 0; ct < 8; ++ct) acc[ct] = (floatx4)0.f;

        #pragma unroll
        for (int ks = 0; ks < 4; ++ks) {
            const float4 f0 = *(const float4*)(x + (size_t)row * DIN + ks * 32 + lg * 8);
            const float4 f1 = *(const float4*)(x + (size_t)row * DIN + ks * 32 + lg * 8 + 4);
            short8 af;
            af[0] = f2bf_bits(f0.x); af[1] = f2bf_bits(f0.y);
            af[2] = f2bf_bits(f0.z); af[3] = f2bf_bits(f0.w);
            af[4] = f2bf_bits(f1.x); af[5] = f2bf_bits(f1.y);
            af[6] = f2bf_bits(f1.z); af[7] = f2bf_bits(f1.w);
            #pragma unroll
            for (int ct = 0; ct < 8; ++ct)
                acc[ct] = __builtin_amdgcn_mfma_f32_16x16x32_bf16(
                    af, bf[ct][ks], acc[ct], 0, 0, 0);
        }

        #pragma unroll
        for (int reg = 0; reg < 4; ++reg) {
            const int r = tile * 16 + lg * 4 + reg;

            // h write (bf16)
            #pragma unroll
            for (int ct = 0; ct < 8; ++ct)
                if (r < n)
                    h[(size_t)r * HC + ct * 16 + l15] =
                        __float2bfloat16(acc[ct][reg] + bc[ct]);

            // fused logits: per-head dot over this row's 128 cols
            float pi[4], pj[4];
            #pragma unroll
            for (int hd = 0; hd < 4; ++hd) {
                float vi = 0.f, vj = 0.f;
                #pragma unroll
                for (int q = 0; q < 2; ++q) {
                    const int ct = hd * 2 + q;
                    const float hv = acc[ct][reg] + bc[ct];
                    vi = fmaf(hv, ai_l[ct], vi);
                    vj = fmaf(hv, aj_l[ct], vj);
                }
                #pragma unroll
                for (int m = 1; m <= 8; m <<= 1) {
                    vi += __shfl_xor(vi, m);
                    vj += __shfl_xor(vj, m);
                }
                pi[hd] = vi; pj[hd] = vj;
            }
            if (l15 < 8 && r < n) {
                const int hd = l15 & 3;
                float wi = pi[0];
                wi = (hd == 1) ? pi[1] : wi;
                wi = (hd == 2) ? pi[2] : wi;
                wi = (hd == 3) ? pi[3] : wi;
                float wj = pj[0];
                wj = (hd == 1) ? pj[1] : wj;
                wj = (hd == 2) ? pj[2] : wj;
                wj = (hd == 3) ? pj[3] : wj;
                if (l15 < 4) ali[(size_t)r * 4 + hd] = wi;
                else         alj[(size_t)r * 4 + hd] = wj;
            }
        }
    }
}

// ---------------------------------------------------------------------------
// CSR build: histogram (+per-edge rank) -> 2-level scan -> atomic-free
// scatter. csr/rank are ushort (n < 2^16, deg_max << 2^16). Consumers add
// boff[i>>8] themselves (no scan3 pass).
// ---------------------------------------------------------------------------
__global__ __launch_bounds__(256) void count_deg(
    const int* __restrict__ src, int* __restrict__ deg,
    unsigned short* __restrict__ rank, int E, int total)
{
    const int e = blockIdx.x * 256 + threadIdx.x;
    if (e >= total) return;
    const int i = (e < E) ? src[e] : (e - E);
    rank[e] = (unsigned short)atomicAdd(&deg[i], 1);
}

// intra-block exclusive scan of deg -> rowptr; per-block sums -> bsum
__global__ __launch_bounds__(256) void scan1(
    const int* __restrict__ deg, int* __restrict__ rowptr,
    int* __restrict__ bsum, int n)
{
    __shared__ int sh[256];
    const int t = threadIdx.x;
    const int i = blockIdx.x * 256 + t;
    const int v = (i < n) ? deg[i] : 0;
    sh[t] = v;
    __syncthreads();
    #pragma unroll
    for (int off = 1; off < 256; off <<= 1) {
        const int u = (t >= off) ? sh[t - off] : 0;
        __syncthreads();
        sh[t] += u;
        __syncthreads();
    }
    if (i < n) rowptr[i] = sh[t] - v;       // exclusive within block
    if (t == 255) bsum[blockIdx.x] = sh[255];
}

// single block: exclusive scan of block sums -> boff
__global__ __launch_bounds__(1024) void scan2(
    const int* __restrict__ bsum, int* __restrict__ boff, int nb)
{
    __shared__ int sh[1024];
    const int t = threadIdx.x;
    const int v = (t < nb) ? bsum[t] : 0;
    sh[t] = v;
    __syncthreads();
    #pragma unroll
    for (int off = 1; off < 1024; off <<= 1) {
        const int u = (t >= off) ? sh[t - off] : 0;
        __syncthreads();
        sh[t] += u;
        __syncthreads();
    }
    if (t < nb) boff[t] = sh[t] - v;
}

// atomic-free scatter: pos = rowptr[i] + boff[i>>8] + rank[e]
__global__ __launch_bounds__(256) void scatter_edges(
    const int* __restrict__ src, const int* __restrict__ dst,
    const unsigned short* __restrict__ rank, const int* __restrict__ rowptr,
    const int* __restrict__ boff, unsigned short* __restrict__ csr,
    int E, int total)
{
    const int e = blockIdx.x * 256 + threadIdx.x;
    if (e >= total) return;
    int i, j;
    if (e < E) { i = src[e]; j = dst[e]; }
    else       { i = e - E;  j = i; }
    csr[rowptr[i] + boff[i >> 8] + (int)rank[e]] = (unsigned short)j;
}

// ---------------------------------------------------------------------------
// One wave per node, single pass, unroll-8 over neighbors (8 independent
// h-row loads in flight). Lane owns 2 output cols of head hh = lane>>4;
// accumulates weighted sum + softmax denominator in identical serial order.
// Normalize + bias + ReLU fused into the single coalesced store.
// ---------------------------------------------------------------------------
__global__ __launch_bounds__(256) void aggregate_csr(
    const int* __restrict__ rowptr, const int* __restrict__ boff,
    const unsigned short* __restrict__ csr,
    const float* __restrict__ ali, const float* __restrict__ alj,
    const __hip_bfloat16* __restrict__ h, const float* __restrict__ bias,
    float* __restrict__ out, int n, int total)
{
    const int lane = threadIdx.x & 63;
    const int hh   = lane >> 4;
    const int gw = (blockIdx.x * 256 + threadIdx.x) >> 6;
    const int nw = (gridDim.x * 256) >> 6;
    const unsigned short* hu = (const unsigned short*)h;

    for (int i = gw; i < n; i += nw) {
        const int rs = rowptr[i] + boff[i >> 8];
        const int re = (i + 1 == n) ? total
                                    : rowptr[i + 1] + boff[(i + 1) >> 8];
        const float aii = ali[(size_t)i * 4 + hh];

        float acc0 = 0.f, acc1 = 0.f, s = 0.f;
        int t = rs;
        for (; t + 8 <= re; t += 8) {
            int jj[8]; float ll[8]; ushort2 uu[8];
            #pragma unroll
            for (int q = 0; q < 8; ++q) jj[q] = csr[t + q];
            #pragma unroll
            for (int q = 0; q < 8; ++q) ll[q] = alj[(size_t)jj[q] * 4 + hh];
            #pragma unroll
            for (int q = 0; q < 8; ++q)
                uu[q] = *(const ushort2*)(hu + (size_t)jj[q] * HC + lane * 2);
            #pragma unroll
            for (int q = 0; q < 8; ++q) {
                float l = aii + ll[q];
                l = l > 0.f ? l : 0.2f * l;
                const float ex = __expf(l);
                s += ex;
                acc0 = fmaf(ex, bfbits2f(uu[q].x), acc0);
                acc1 = fmaf(ex, bfbits2f(uu[q].y), acc1);
            }
        }
        for (; t + 4 <= re; t += 4) {
            int jj[4]; float ll[4]; ushort2 uu[4];
            #pragma unroll
            for (int q = 0; q < 4; ++q) jj[q] = csr[t + q];
            #pragma unroll
            for (int q = 0; q < 4; ++q) ll[q] = alj[(size_t)jj[q] * 4 + hh];
            #pragma unroll
            for (int q = 0; q < 4; ++q)
                uu[q] = *(const ushort2*)(hu + (size_t)jj[q] * HC + lane * 2);
            #pragma unroll
            for (int q = 0; q < 4; ++q) {
                float l = aii + ll[q];
                l = l > 0.f ? l : 0.2f * l;
                const float ex = __expf(l);
                s += ex;
                acc0 = fmaf(ex, bfbits2f(uu[q].x), acc0);
                acc1 = fmaf(ex, bfbits2f(uu[q].y), acc1);
            }
        }
        for (; t < re; ++t) {
            const int j = csr[t];
            float l = aii + alj[(size_t)j * 4 + hh];
            l = l > 0.f ? l : 0.2f * l;
            const float ex = __expf(l);
            s += ex;
            const ushort2 u = *(const ushort2*)(hu + (size_t)j * HC + lane * 2);
            acc0 = fmaf(ex, bfbits2f(u.x), acc0);
            acc1 = fmaf(ex, bfbits2f(u.y), acc1);
        }
        const float inv = 1.0f / s;
        float o0 = fmaf(acc0, inv, bias[lane * 2]);
        float o1 = fmaf(acc1, inv, bias[lane * 2 + 1]);
        float2 ov;
        ov.x = o0 > 0.f ? o0 : 0.f;
        ov.y = o1 > 0.f ? o1 : 0.f;
        *(float2*)(out + (size_t)i * HC + lane * 2) = ov;
    }
}

extern "C" void kernel_launch(void* const* d_in, const int* in_sizes, int n_in,
                              void* d_out, int out_size, void* d_ws, size_t ws_size,
                              hipStream_t stream)
{
    const float* x    = (const float*)d_in[0];
    const int*   ei   = (const int*)d_in[1];     // int32 (harness convention)
    const float* W    = (const float*)d_in[2];
    const float* b    = (const float*)d_in[3];
    const float* att  = (const float*)d_in[4];
    const float* bias = (const float*)d_in[5];

    const int n     = in_sizes[0] / DIN;   // 50000
    const int E     = in_sizes[1] / 2;     // 800000
    const int total = E + n;

    const int* src = ei;        // e_i (segment index)
    const int* dst = ei + E;    // e_j (gather index)

    // workspace layout (~18 MB), 256B-aligned slices
    char* ws = (char*)d_ws;
    size_t off = 0;
    auto take = [&](size_t bytes) {
        char* p = ws + off;
        off += (bytes + 255) & ~(size_t)255;
        return p;
    };
    const int nb = (n + 255) / 256;                     // scan blocks (196)
    __hip_bfloat16* h   = (__hip_bfloat16*)take((size_t)n * HC * 2);
    float* ali    = (float*)take((size_t)n * NH * 4);
    float* alj    = (float*)take((size_t)n * NH * 4);
    int*   rowptr = (int*)take((size_t)(n + 1) * 4);
    int*   deg    = (int*)take((size_t)n * 4);
    int*   bsum   = (int*)take((size_t)nb * 4);
    int*   boff   = (int*)take((size_t)nb * 4);
    unsigned short* rank = (unsigned short*)take((size_t)total * 2);
    unsigned short* csr  = (unsigned short*)take((size_t)total * 2);

    float* out = (float*)d_out;

    hipMemsetAsync(deg, 0, (size_t)n * 4, stream);

    const int ntiles = (n + 15) / 16;
    gemm_h<<<256, 256, 0, stream>>>(x, W, b, att, h, ali, alj, n, ntiles);

    const int eb = (total + 255) / 256;
    count_deg<<<eb, 256, 0, stream>>>(src, deg, rank, E, total);
    scan1<<<nb, 256, 0, stream>>>(deg, rowptr, bsum, n);
    scan2<<<1, 1024, 0, stream>>>(bsum, boff, nb);
    scatter_edges<<<eb, 256, 0, stream>>>(src, dst, rank, rowptr, boff, csr,
                                          E, total);

    const int nodeBlocks = (n + 3) / 4;            // 4 waves/block, 1 node/wave
    aggregate_csr<<<nodeBlocks, 256, 0, stream>>>(rowptr, boff, csr, ali, alj,
                                                  h, bias, out, n, total);
}

// Round 8
// 117.555 us; speedup vs baseline: 5.7105x; 1.0440x over previous
//
#include <hip/hip_runtime.h>
#include <hip/hip_bf16.h>

#define DIN 128
#define HC  128
#define NH  4

typedef __attribute__((ext_vector_type(8))) short short8;
typedef __attribute__((ext_vector_type(4))) float floatx4;

__device__ inline short f2bf_bits(float f) {
    __hip_bfloat16 t = __float2bfloat16(f);
    return *reinterpret_cast<short*>(&t);
}
__device__ inline float bfbits2f(unsigned short u) {
    union { unsigned int i; float f; } c; c.i = ((unsigned int)u) << 16; return c.f;
}

// ---------------------------------------------------------------------------
// h = bf16(x @ W + b) via MFMA 16x16x32 bf16, with FUSED per-node attention
// logits (ali/alj) and FUSED deg-zeroing (replaces a 43us runtime fill kernel;
// count_deg runs after us in stream order).
// ---------------------------------------------------------------------------
__global__ __launch_bounds__(256) void gemm_h(
    const float* __restrict__ x, const float* __restrict__ W,
    const float* __restrict__ b, const float* __restrict__ att,
    __hip_bfloat16* __restrict__ h, float* __restrict__ ali,
    float* __restrict__ alj, int* __restrict__ deg, int n, int ntiles)
{
    // zero deg[] (one int per thread; grid 256x256 = 65536 >= n)
    {
        const int idx = blockIdx.x * 256 + threadIdx.x;
        if (idx < n) deg[idx] = 0;
    }

    __shared__ __hip_bfloat16 Wt[DIN][136];
    for (int idx = threadIdx.x; idx < DIN * HC; idx += 256) {
        const int k = idx >> 7, c = idx & 127;
        Wt[c][k] = __float2bfloat16(W[idx]);
    }
    __syncthreads();

    const int lane = threadIdx.x & 63;
    const int l15 = lane & 15, lg = lane >> 4;

    short8 bf[8][4];
    #pragma unroll
    for (int ct = 0; ct < 8; ++ct)
        #pragma unroll
        for (int ks = 0; ks < 4; ++ks)
            bf[ct][ks] = *(const short8*)(&Wt[ct * 16 + l15][ks * 32 + lg * 8]);

    float bc[8], ai_l[8], aj_l[8];
    #pragma unroll
    for (int ct = 0; ct < 8; ++ct) {
        bc[ct]   = b[ct * 16 + l15];
        ai_l[ct] = att[(ct >> 1) * 64 + (ct & 1) * 16 + l15];
        aj_l[ct] = att[(ct >> 1) * 64 + 32 + (ct & 1) * 16 + l15];
    }

    const int gw = (blockIdx.x * 256 + threadIdx.x) >> 6;
    const int nw = (gridDim.x * 256) >> 6;
    for (int tile = gw; tile < ntiles; tile += nw) {
        int row = tile * 16 + l15;
        if (row >= n) row = n - 1;              // safe duplicate load
        floatx4 acc[8];
        #pragma unroll
        for (int ct = 0; ct < 8; ++ct) acc[ct] = (floatx4)0.f;

        #pragma unroll
        for (int ks = 0; ks < 4; ++ks) {
            const float4 f0 = *(const float4*)(x + (size_t)row * DIN + ks * 32 + lg * 8);
            const float4 f1 = *(const float4*)(x + (size_t)row * DIN + ks * 32 + lg * 8 + 4);
            short8 af;
            af[0] = f2bf_bits(f0.x); af[1] = f2bf_bits(f0.y);
            af[2] = f2bf_bits(f0.z); af[3] = f2bf_bits(f0.w);
            af[4] = f2bf_bits(f1.x); af[5] = f2bf_bits(f1.y);
            af[6] = f2bf_bits(f1.z); af[7] = f2bf_bits(f1.w);
            #pragma unroll
            for (int ct = 0; ct < 8; ++ct)
                acc[ct] = __builtin_amdgcn_mfma_f32_16x16x32_bf16(
                    af, bf[ct][ks], acc[ct], 0, 0, 0);
        }

        #pragma unroll
        for (int reg = 0; reg < 4; ++reg) {
            const int r = tile * 16 + lg * 4 + reg;

            // h write (bf16)
            #pragma unroll
            for (int ct = 0; ct < 8; ++ct)
                if (r < n)
                    h[(size_t)r * HC + ct * 16 + l15] =
                        __float2bfloat16(acc[ct][reg] + bc[ct]);

            // fused logits: per-head dot over this row's 128 cols
            float pi[4], pj[4];
            #pragma unroll
            for (int hd = 0; hd < 4; ++hd) {
                float vi = 0.f, vj = 0.f;
                #pragma unroll
                for (int q = 0; q < 2; ++q) {
                    const int ct = hd * 2 + q;
                    const float hv = acc[ct][reg] + bc[ct];
                    vi = fmaf(hv, ai_l[ct], vi);
                    vj = fmaf(hv, aj_l[ct], vj);
                }
                #pragma unroll
                for (int m = 1; m <= 8; m <<= 1) {
                    vi += __shfl_xor(vi, m);
                    vj += __shfl_xor(vj, m);
                }
                pi[hd] = vi; pj[hd] = vj;
            }
            if (l15 < 8 && r < n) {
                const int hd = l15 & 3;
                float wi = pi[0];
                wi = (hd == 1) ? pi[1] : wi;
                wi = (hd == 2) ? pi[2] : wi;
                wi = (hd == 3) ? pi[3] : wi;
                float wj = pj[0];
                wj = (hd == 1) ? pj[1] : wj;
                wj = (hd == 2) ? pj[2] : wj;
                wj = (hd == 3) ? pj[3] : wj;
                if (l15 < 4) ali[(size_t)r * 4 + hd] = wi;
                else         alj[(size_t)r * 4 + hd] = wj;
            }
        }
    }
}

// ---------------------------------------------------------------------------
// CSR build: histogram (+per-edge rank) -> 2-level scan -> atomic-free
// scatter. csr/rank are ushort (n < 2^16, deg_max << 2^16). Consumers add
// boff[i>>8] themselves (no scan3 pass).
// ---------------------------------------------------------------------------
__global__ __launch_bounds__(256) void count_deg(
    const int* __restrict__ src, int* __restrict__ deg,
    unsigned short* __restrict__ rank, int E, int total)
{
    const int e = blockIdx.x * 256 + threadIdx.x;
    if (e >= total) return;
    const int i = (e < E) ? src[e] : (e - E);
    rank[e] = (unsigned short)atomicAdd(&deg[i], 1);
}

// intra-block exclusive scan of deg -> rowptr; per-block sums -> bsum
__global__ __launch_bounds__(256) void scan1(
    const int* __restrict__ deg, int* __restrict__ rowptr,
    int* __restrict__ bsum, int n)
{
    __shared__ int sh[256];
    const int t = threadIdx.x;
    const int i = blockIdx.x * 256 + t;
    const int v = (i < n) ? deg[i] : 0;
    sh[t] = v;
    __syncthreads();
    #pragma unroll
    for (int off = 1; off < 256; off <<= 1) {
        const int u = (t >= off) ? sh[t - off] : 0;
        __syncthreads();
        sh[t] += u;
        __syncthreads();
    }
    if (i < n) rowptr[i] = sh[t] - v;       // exclusive within block
    if (t == 255) bsum[blockIdx.x] = sh[255];
}

// single block: exclusive scan of block sums -> boff
__global__ __launch_bounds__(1024) void scan2(
    const int* __restrict__ bsum, int* __restrict__ boff, int nb)
{
    __shared__ int sh[1024];
    const int t = threadIdx.x;
    const int v = (t < nb) ? bsum[t] : 0;
    sh[t] = v;
    __syncthreads();
    #pragma unroll
    for (int off = 1; off < 1024; off <<= 1) {
        const int u = (t >= off) ? sh[t - off] : 0;
        __syncthreads();
        sh[t] += u;
        __syncthreads();
    }
    if (t < nb) boff[t] = sh[t] - v;
}

// atomic-free scatter: pos = rowptr[i] + boff[i>>8] + rank[e]
__global__ __launch_bounds__(256) void scatter_edges(
    const int* __restrict__ src, const int* __restrict__ dst,
    const unsigned short* __restrict__ rank, const int* __restrict__ rowptr,
    const int* __restrict__ boff, unsigned short* __restrict__ csr,
    int E, int total)
{
    const int e = blockIdx.x * 256 + threadIdx.x;
    if (e >= total) return;
    int i, j;
    if (e < E) { i = src[e]; j = dst[e]; }
    else       { i = e - E;  j = i; }
    csr[rowptr[i] + boff[i >> 8] + (int)rank[e]] = (unsigned short)j;
}

// ---------------------------------------------------------------------------
// One wave per node, single pass, unroll-8 over neighbors (8 independent
// h-row loads in flight). Lane owns 2 output cols of head hh = lane>>4;
// accumulates weighted sum + softmax denominator in identical serial order.
// Normalize + bias + ReLU fused into the single coalesced store.
// ---------------------------------------------------------------------------
__global__ __launch_bounds__(256) void aggregate_csr(
    const int* __restrict__ rowptr, const int* __restrict__ boff,
    const unsigned short* __restrict__ csr,
    const float* __restrict__ ali, const float* __restrict__ alj,
    const __hip_bfloat16* __restrict__ h, const float* __restrict__ bias,
    float* __restrict__ out, int n, int total)
{
    const int lane = threadIdx.x & 63;
    const int hh   = lane >> 4;
    const int gw = (blockIdx.x * 256 + threadIdx.x) >> 6;
    const int nw = (gridDim.x * 256) >> 6;
    const unsigned short* hu = (const unsigned short*)h;

    for (int i = gw; i < n; i += nw) {
        const int rs = rowptr[i] + boff[i >> 8];
        const int re = (i + 1 == n) ? total
                                    : rowptr[i + 1] + boff[(i + 1) >> 8];
        const float aii = ali[(size_t)i * 4 + hh];

        float acc0 = 0.f, acc1 = 0.f, s = 0.f;
        int t = rs;
        for (; t + 8 <= re; t += 8) {
            int jj[8]; float ll[8]; ushort2 uu[8];
            #pragma unroll
            for (int q = 0; q < 8; ++q) jj[q] = csr[t + q];
            #pragma unroll
            for (int q = 0; q < 8; ++q) ll[q] = alj[(size_t)jj[q] * 4 + hh];
            #pragma unroll
            for (int q = 0; q < 8; ++q)
                uu[q] = *(const ushort2*)(hu + (size_t)jj[q] * HC + lane * 2);
            #pragma unroll
            for (int q = 0; q < 8; ++q) {
                float l = aii + ll[q];
                l = l > 0.f ? l : 0.2f * l;
                const float ex = __expf(l);
                s += ex;
                acc0 = fmaf(ex, bfbits2f(uu[q].x), acc0);
                acc1 = fmaf(ex, bfbits2f(uu[q].y), acc1);
            }
        }
        for (; t + 4 <= re; t += 4) {
            int jj[4]; float ll[4]; ushort2 uu[4];
            #pragma unroll
            for (int q = 0; q < 4; ++q) jj[q] = csr[t + q];
            #pragma unroll
            for (int q = 0; q < 4; ++q) ll[q] = alj[(size_t)jj[q] * 4 + hh];
            #pragma unroll
            for (int q = 0; q < 4; ++q)
                uu[q] = *(const ushort2*)(hu + (size_t)jj[q] * HC + lane * 2);
            #pragma unroll
            for (int q = 0; q < 4; ++q) {
                float l = aii + ll[q];
                l = l > 0.f ? l : 0.2f * l;
                const float ex = __expf(l);
                s += ex;
                acc0 = fmaf(ex, bfbits2f(uu[q].x), acc0);
                acc1 = fmaf(ex, bfbits2f(uu[q].y), acc1);
            }
        }
        for (; t < re; ++t) {
            const int j = csr[t];
            float l = aii + alj[(size_t)j * 4 + hh];
            l = l > 0.f ? l : 0.2f * l;
            const float ex = __expf(l);
            s += ex;
            const ushort2 u = *(const ushort2*)(hu + (size_t)j * HC + lane * 2);
            acc0 = fmaf(ex, bfbits2f(u.x), acc0);
            acc1 = fmaf(ex, bfbits2f(u.y), acc1);
        }
        const float inv = 1.0f / s;
        float o0 = fmaf(acc0, inv, bias[lane * 2]);
        float o1 = fmaf(acc1, inv, bias[lane * 2 + 1]);
        float2 ov;
        ov.x = o0 > 0.f ? o0 : 0.f;
        ov.y = o1 > 0.f ? o1 : 0.f;
        *(float2*)(out + (size_t)i * HC + lane * 2) = ov;
    }
}

extern "C" void kernel_launch(void* const* d_in, const int* in_sizes, int n_in,
                              void* d_out, int out_size, void* d_ws, size_t ws_size,
                              hipStream_t stream)
{
    const float* x    = (const float*)d_in[0];
    const int*   ei   = (const int*)d_in[1];     // int32 (harness convention)
    const float* W    = (const float*)d_in[2];
    const float* b    = (const float*)d_in[3];
    const float* att  = (const float*)d_in[4];
    const float* bias = (const float*)d_in[5];

    const int n     = in_sizes[0] / DIN;   // 50000
    const int E     = in_sizes[1] / 2;     // 800000
    const int total = E + n;

    const int* src = ei;        // e_i (segment index)
    const int* dst = ei + E;    // e_j (gather index)

    // workspace layout (~18 MB), 256B-aligned slices
    char* ws = (char*)d_ws;
    size_t off = 0;
    auto take = [&](size_t bytes) {
        char* p = ws + off;
        off += (bytes + 255) & ~(size_t)255;
        return p;
    };
    const int nb = (n + 255) / 256;                     // scan blocks (196)
    __hip_bfloat16* h   = (__hip_bfloat16*)take((size_t)n * HC * 2);
    float* ali    = (float*)take((size_t)n * NH * 4);
    float* alj    = (float*)take((size_t)n * NH * 4);
    int*   rowptr = (int*)take((size_t)(n + 1) * 4);
    int*   deg    = (int*)take((size_t)n * 4);
    int*   bsum   = (int*)take((size_t)nb * 4);
    int*   boff   = (int*)take((size_t)nb * 4);
    unsigned short* rank = (unsigned short*)take((size_t)total * 2);
    unsigned short* csr  = (unsigned short*)take((size_t)total * 2);

    float* out = (float*)d_out;

    const int ntiles = (n + 15) / 16;
    gemm_h<<<256, 256, 0, stream>>>(x, W, b, att, h, ali, alj, deg, n, ntiles);

    const int eb = (total + 255) / 256;
    count_deg<<<eb, 256, 0, stream>>>(src, deg, rank, E, total);
    scan1<<<nb, 256, 0, stream>>>(deg, rowptr, bsum, n);
    scan2<<<1, 1024, 0, stream>>>(bsum, boff, nb);
    scatter_edges<<<eb, 256, 0, stream>>>(src, dst, rank, rowptr, boff, csr,
                                          E, total);

    const int nodeBlocks = (n + 3) / 4;            // 4 waves/block, 1 node/wave
    aggregate_csr<<<nodeBlocks, 256, 0, stream>>>(rowptr, boff, csr, ali, alj,
                                                  h, bias, out, n, total);
}

// Round 9
// 106.390 us; speedup vs baseline: 6.3098x; 1.1049x over previous
//
#include <hip/hip_runtime.h>
#include <hip/hip_bf16.h>

#define DIN 128
#define HC  128
#define NH  4

typedef __attribute__((ext_vector_type(8))) short short8;
typedef __attribute__((ext_vector_type(4))) float floatx4;

__device__ inline short f2bf_bits(float f) {
    __hip_bfloat16 t = __float2bfloat16(f);
    return *reinterpret_cast<short*>(&t);
}
__device__ inline float bfbits2f(unsigned short u) {
    union { unsigned int i; float f; } c; c.i = ((unsigned int)u) << 16; return c.f;
}

// ---------------------------------------------------------------------------
// zero deg[] before the fused gemm+histogram kernel
// ---------------------------------------------------------------------------
__global__ __launch_bounds__(256) void zero_deg(int* __restrict__ deg, int n)
{
    const int i = blockIdx.x * 256 + threadIdx.x;
    if (i < n) deg[i] = 0;
}

// ---------------------------------------------------------------------------
// FUSED kernel, block-range split:
//   blocks [0, GB)      : h = bf16(x @ W + b) via MFMA + fused ali/alj logits
//   blocks [GB, GB+CB)  : edge histogram (deg atomics + per-edge rank)
// The two workloads hit different pipes (MFMA/LDS vs coherence-point atomics)
// and share the GPU instead of running serially.
// ---------------------------------------------------------------------------
#define GB 256
#define CB 1024
__global__ __launch_bounds__(256) void gemm_count(
    const float* __restrict__ x, const float* __restrict__ W,
    const float* __restrict__ b, const float* __restrict__ att,
    __hip_bfloat16* __restrict__ h, float* __restrict__ ali,
    float* __restrict__ alj,
    const int* __restrict__ src, int* __restrict__ deg,
    unsigned short* __restrict__ rank,
    int n, int ntiles, int E, int total)
{
    __shared__ __hip_bfloat16 Wt[DIN][136];

    if (blockIdx.x >= GB) {
        // ---------------- histogram part ----------------
        for (int e = (blockIdx.x - GB) * 256 + threadIdx.x; e < total;
             e += CB * 256) {
            const int i = (e < E) ? src[e] : (e - E);
            rank[e] = (unsigned short)atomicAdd(&deg[i], 1);
        }
        return;
    }

    // ---------------- GEMM part ----------------
    for (int idx = threadIdx.x; idx < DIN * HC; idx += 256) {
        const int k = idx >> 7, c = idx & 127;
        Wt[c][k] = __float2bfloat16(W[idx]);
    }
    __syncthreads();

    const int lane = threadIdx.x & 63;
    const int l15 = lane & 15, lg = lane >> 4;

    short8 bf[8][4];
    #pragma unroll
    for (int ct = 0; ct < 8; ++ct)
        #pragma unroll
        for (int ks = 0; ks < 4; ++ks)
            bf[ct][ks] = *(const short8*)(&Wt[ct * 16 + l15][ks * 32 + lg * 8]);

    float bc[8], ai_l[8], aj_l[8];
    #pragma unroll
    for (int ct = 0; ct < 8; ++ct) {
        bc[ct]   = b[ct * 16 + l15];
        ai_l[ct] = att[(ct >> 1) * 64 + (ct & 1) * 16 + l15];
        aj_l[ct] = att[(ct >> 1) * 64 + 32 + (ct & 1) * 16 + l15];
    }

    const int gw = (blockIdx.x * 256 + threadIdx.x) >> 6;
    const int nw = (GB * 256) >> 6;
    for (int tile = gw; tile < ntiles; tile += nw) {
        int row = tile * 16 + l15;
        if (row >= n) row = n - 1;              // safe duplicate load
        floatx4 acc[8];
        #pragma unroll
        for (int ct = 0; ct < 8; ++ct) acc[ct] = (floatx4)0.f;

        #pragma unroll
        for (int ks = 0; ks < 4; ++ks) {
            const float4 f0 = *(const float4*)(x + (size_t)row * DIN + ks * 32 + lg * 8);
            const float4 f1 = *(const float4*)(x + (size_t)row * DIN + ks * 32 + lg * 8 + 4);
            short8 af;
            af[0] = f2bf_bits(f0.x); af[1] = f2bf_bits(f0.y);
            af[2] = f2bf_bits(f0.z); af[3] = f2bf_bits(f0.w);
            af[4] = f2bf_bits(f1.x); af[5] = f2bf_bits(f1.y);
            af[6] = f2bf_bits(f1.z); af[7] = f2bf_bits(f1.w);
            #pragma unroll
            for (int ct = 0; ct < 8; ++ct)
                acc[ct] = __builtin_amdgcn_mfma_f32_16x16x32_bf16(
                    af, bf[ct][ks], acc[ct], 0, 0, 0);
        }

        #pragma unroll
        for (int reg = 0; reg < 4; ++reg) {
            const int r = tile * 16 + lg * 4 + reg;

            // h write (bf16)
            #pragma unroll
            for (int ct = 0; ct < 8; ++ct)
                if (r < n)
                    h[(size_t)r * HC + ct * 16 + l15] =
                        __float2bfloat16(acc[ct][reg] + bc[ct]);

            // fused logits: per-head dot over this row's 128 cols
            float pi[4], pj[4];
            #pragma unroll
            for (int hd = 0; hd < 4; ++hd) {
                float vi = 0.f, vj = 0.f;
                #pragma unroll
                for (int q = 0; q < 2; ++q) {
                    const int ct = hd * 2 + q;
                    const float hv = acc[ct][reg] + bc[ct];
                    vi = fmaf(hv, ai_l[ct], vi);
                    vj = fmaf(hv, aj_l[ct], vj);
                }
                #pragma unroll
                for (int m = 1; m <= 8; m <<= 1) {
                    vi += __shfl_xor(vi, m);
                    vj += __shfl_xor(vj, m);
                }
                pi[hd] = vi; pj[hd] = vj;
            }
            if (l15 < 8 && r < n) {
                const int hd = l15 & 3;
                float wi = pi[0];
                wi = (hd == 1) ? pi[1] : wi;
                wi = (hd == 2) ? pi[2] : wi;
                wi = (hd == 3) ? pi[3] : wi;
                float wj = pj[0];
                wj = (hd == 1) ? pj[1] : wj;
                wj = (hd == 2) ? pj[2] : wj;
                wj = (hd == 3) ? pj[3] : wj;
                if (l15 < 4) ali[(size_t)r * 4 + hd] = wi;
                else         alj[(size_t)r * 4 + hd] = wj;
            }
        }
    }
}

// intra-block exclusive scan of deg -> rowptr; per-block sums -> bsum
__global__ __launch_bounds__(256) void scan1(
    const int* __restrict__ deg, int* __restrict__ rowptr,
    int* __restrict__ bsum, int n)
{
    __shared__ int sh[256];
    const int t = threadIdx.x;
    const int i = blockIdx.x * 256 + t;
    const int v = (i < n) ? deg[i] : 0;
    sh[t] = v;
    __syncthreads();
    #pragma unroll
    for (int off = 1; off < 256; off <<= 1) {
        const int u = (t >= off) ? sh[t - off] : 0;
        __syncthreads();
        sh[t] += u;
        __syncthreads();
    }
    if (i < n) rowptr[i] = sh[t] - v;       // exclusive within block
    if (t == 255) bsum[blockIdx.x] = sh[255];
}

// single block: exclusive scan of block sums -> boff
__global__ __launch_bounds__(1024) void scan2(
    const int* __restrict__ bsum, int* __restrict__ boff, int nb)
{
    __shared__ int sh[1024];
    const int t = threadIdx.x;
    const int v = (t < nb) ? bsum[t] : 0;
    sh[t] = v;
    __syncthreads();
    #pragma unroll
    for (int off = 1; off < 1024; off <<= 1) {
        const int u = (t >= off) ? sh[t - off] : 0;
        __syncthreads();
        sh[t] += u;
        __syncthreads();
    }
    if (t < nb) boff[t] = sh[t] - v;
}

// atomic-free scatter: pos = rowptr[i] + boff[i>>8] + rank[e]
__global__ __launch_bounds__(256) void scatter_edges(
    const int* __restrict__ src, const int* __restrict__ dst,
    const unsigned short* __restrict__ rank, const int* __restrict__ rowptr,
    const int* __restrict__ boff, unsigned short* __restrict__ csr,
    int E, int total)
{
    const int e = blockIdx.x * 256 + threadIdx.x;
    if (e >= total) return;
    int i, j;
    if (e < E) { i = src[e]; j = dst[e]; }
    else       { i = e - E;  j = i; }
    csr[rowptr[i] + boff[i >> 8] + (int)rank[e]] = (unsigned short)j;
}

// ---------------------------------------------------------------------------
// One wave per node, single pass, unroll-8 over neighbors (8 independent
// h-row loads in flight). Lane owns 2 output cols of head hh = lane>>4;
// accumulates weighted sum + softmax denominator in identical serial order.
// Normalize + bias + ReLU fused into the single coalesced store.
// ---------------------------------------------------------------------------
__global__ __launch_bounds__(256) void aggregate_csr(
    const int* __restrict__ rowptr, const int* __restrict__ boff,
    const unsigned short* __restrict__ csr,
    const float* __restrict__ ali, const float* __restrict__ alj,
    const __hip_bfloat16* __restrict__ h, const float* __restrict__ bias,
    float* __restrict__ out, int n, int total)
{
    const int lane = threadIdx.x & 63;
    const int hh   = lane >> 4;
    const int gw = (blockIdx.x * 256 + threadIdx.x) >> 6;
    const int nw = (gridDim.x * 256) >> 6;
    const unsigned short* hu = (const unsigned short*)h;
    const float b0 = bias[lane * 2], b1 = bias[lane * 2 + 1];

    for (int i = gw; i < n; i += nw) {
        const int rs = rowptr[i] + boff[i >> 8];
        const int re = (i + 1 == n) ? total
                                    : rowptr[i + 1] + boff[(i + 1) >> 8];
        const float aii = ali[(size_t)i * 4 + hh];

        float acc0 = 0.f, acc1 = 0.f, s = 0.f;
        int t = rs;
        for (; t + 8 <= re; t += 8) {
            int jj[8]; float ll[8]; ushort2 uu[8];
            #pragma unroll
            for (int q = 0; q < 8; ++q) jj[q] = csr[t + q];
            #pragma unroll
            for (int q = 0; q < 8; ++q) ll[q] = alj[(size_t)jj[q] * 4 + hh];
            #pragma unroll
            for (int q = 0; q < 8; ++q)
                uu[q] = *(const ushort2*)(hu + (size_t)jj[q] * HC + lane * 2);
            #pragma unroll
            for (int q = 0; q < 8; ++q) {
                float l = aii + ll[q];
                l = l > 0.f ? l : 0.2f * l;
                const float ex = __expf(l);
                s += ex;
                acc0 = fmaf(ex, bfbits2f(uu[q].x), acc0);
                acc1 = fmaf(ex, bfbits2f(uu[q].y), acc1);
            }
        }
        for (; t + 4 <= re; t += 4) {
            int jj[4]; float ll[4]; ushort2 uu[4];
            #pragma unroll
            for (int q = 0; q < 4; ++q) jj[q] = csr[t + q];
            #pragma unroll
            for (int q = 0; q < 4; ++q) ll[q] = alj[(size_t)jj[q] * 4 + hh];
            #pragma unroll
            for (int q = 0; q < 4; ++q)
                uu[q] = *(const ushort2*)(hu + (size_t)jj[q] * HC + lane * 2);
            #pragma unroll
            for (int q = 0; q < 4; ++q) {
                float l = aii + ll[q];
                l = l > 0.f ? l : 0.2f * l;
                const float ex = __expf(l);
                s += ex;
                acc0 = fmaf(ex, bfbits2f(uu[q].x), acc0);
                acc1 = fmaf(ex, bfbits2f(uu[q].y), acc1);
            }
        }
        for (; t < re; ++t) {
            const int j = csr[t];
            float l = aii + alj[(size_t)j * 4 + hh];
            l = l > 0.f ? l : 0.2f * l;
            const float ex = __expf(l);
            s += ex;
            const ushort2 u = *(const ushort2*)(hu + (size_t)j * HC + lane * 2);
            acc0 = fmaf(ex, bfbits2f(u.x), acc0);
            acc1 = fmaf(ex, bfbits2f(u.y), acc1);
        }
        const float inv = 1.0f / s;
        float o0 = fmaf(acc0, inv, b0);
        float o1 = fmaf(acc1, inv, b1);
        float2 ov;
        ov.x = o0 > 0.f ? o0 : 0.f;
        ov.y = o1 > 0.f ? o1 : 0.f;
        *(float2*)(out + (size_t)i * HC + lane * 2) = ov;
    }
}

extern "C" void kernel_launch(void* const* d_in, const int* in_sizes, int n_in,
                              void* d_out, int out_size, void* d_ws, size_t ws_size,
                              hipStream_t stream)
{
    const float* x    = (const float*)d_in[0];
    const int*   ei   = (const int*)d_in[1];     // int32 (harness convention)
    const float* W    = (const float*)d_in[2];
    const float* b    = (const float*)d_in[3];
    const float* att  = (const float*)d_in[4];
    const float* bias = (const float*)d_in[5];

    const int n     = in_sizes[0] / DIN;   // 50000
    const int E     = in_sizes[1] / 2;     // 800000
    const int total = E + n;

    const int* src = ei;        // e_i (segment index)
    const int* dst = ei + E;    // e_j (gather index)

    // workspace layout (~18 MB), 256B-aligned slices
    char* ws = (char*)d_ws;
    size_t off = 0;
    auto take = [&](size_t bytes) {
        char* p = ws + off;
        off += (bytes + 255) & ~(size_t)255;
        return p;
    };
    const int nb = (n + 255) / 256;                     // scan blocks (196)
    __hip_bfloat16* h   = (__hip_bfloat16*)take((size_t)n * HC * 2);
    float* ali    = (float*)take((size_t)n * NH * 4);
    float* alj    = (float*)take((size_t)n * NH * 4);
    int*   rowptr = (int*)take((size_t)(n + 1) * 4);
    int*   deg    = (int*)take((size_t)n * 4);
    int*   bsum   = (int*)take((size_t)nb * 4);
    int*   boff   = (int*)take((size_t)nb * 4);
    unsigned short* rank = (unsigned short*)take((size_t)total * 2);
    unsigned short* csr  = (unsigned short*)take((size_t)total * 2);

    float* out = (float*)d_out;

    zero_deg<<<nb, 256, 0, stream>>>(deg, n);

    const int ntiles = (n + 15) / 16;
    gemm_count<<<GB + CB, 256, 0, stream>>>(x, W, b, att, h, ali, alj,
                                            src, deg, rank, n, ntiles, E, total);

    scan1<<<nb, 256, 0, stream>>>(deg, rowptr, bsum, n);
    scan2<<<1, 1024, 0, stream>>>(bsum, boff, nb);

    const int eb = (total + 255) / 256;
    scatter_edges<<<eb, 256, 0, stream>>>(src, dst, rank, rowptr, boff, csr,
                                          E, total);

    const int nodeBlocks = (n + 3) / 4;            // 4 waves/block, 1 node/wave
    aggregate_csr<<<nodeBlocks, 256, 0, stream>>>(rowptr, boff, csr, ali, alj,
                                                  h, bias, out, n, total);
}